// Round 4
// baseline (81.768 us; speedup 1.0000x reference)
//
#include <hip/hip_runtime.h>
#include <math.h>

#define KP   125        // 5*5*5 filter taps
#define VOL7 344        // 7*7*7 = 343 zero-frame volume, rounded to /4
#define FPB  4          // one wave per filter, 4 filters per 256-thread block

__global__ __launch_bounds__(FPB * 64) void fastrot_kernel(
    const float* __restrict__ vol,      // N*125
    const float* __restrict__ theta_v,  // N*3
    const float* __restrict__ theta,    // N
    float* __restrict__ out)            // N*125
{
    __shared__ __align__(16) float pad[FPB][VOL7];

    const int lane = threadIdx.x & 63;
    const int wv   = threadIdx.x >> 6;
    const long long n = (long long)blockIdx.x * FPB + wv;

    // ---- zero-fill 7^3 frame (intra-wave ordering; no barriers anywhere) ----
    float4* p4 = (float4*)(&pad[wv][0]);
    const float4 z4 = make_float4(0.f, 0.f, 0.f, 0.f);
    p4[lane] = z4;
    if (lane < (VOL7 / 4 - 64)) p4[lane + 64] = z4;   // 86 float4 total

    // ---- load this filter's 125 values (coalesced, 2 loads/lane) ----
    const float* vn = vol + n * (long long)KP;
    const int p0 = lane, p1 = lane + 64;
    const float fv0 = vn[p0];
    const float fv1 = (p1 < KP) ? vn[p1] : 0.0f;

    // p -> (i,j,l), exact magic-mul for p < 128
    const int i0 = (p0 * 41) >> 10;
    const int q0 = (p0 * 205) >> 10;
    const int j0 = q0 - i0 * 5;
    const int l0 = p0 - q0 * 5;
    const int i1 = (p1 * 41) >> 10;
    const int q1 = (p1 * 205) >> 10;
    const int j1 = q1 - i1 * 5;
    const int l1 = p1 - q1 * 5;

    // ---- scatter interior into frame: idx = 49(i+1)+7(j+1)+(l+1) ----
    pad[wv][i0 * 49 + j0 * 7 + l0 + 57] = fv0;
    if (p1 < KP) pad[wv][i1 * 49 + j1 * 7 + l1 + 57] = fv1;

    // ---- Rodrigues, redundant in all lanes (VALU has slack; no barrier) ----
    const float ax = theta_v[n * 3 + 0];
    const float ay = theta_v[n * 3 + 1];
    const float az = theta_v[n * 3 + 2];
    const float th = theta[n];
    const float d2  = ax * ax + ay * ay + az * az;
    const float inv = rsqrtf(fmaxf(d2, 1e-24f));
    const float vx = ax * inv, vy = ay * inv, vz = az * inv;
    float s, cth;
    __sincosf(th, &s, &cth);
    const float c = 1.0f - cth;

    const float R00 = 1.0f - c * (vy * vy + vz * vz);
    const float R01 = -s * vz + c * (vx * vy);
    const float R02 =  s * vy + c * (vx * vz);
    const float R10 =  s * vz + c * (vx * vy);
    const float R11 = 1.0f - c * (vx * vx + vz * vz);
    const float R12 = -s * vx + c * (vy * vz);
    const float R20 = -s * vy + c * (vx * vz);
    const float R21 =  s * vx + c * (vy * vz);
    const float R22 = 1.0f - c * (vx * vx + vy * vy);

    const float* pw = &pad[wv][0];
    float* on = out + n * (long long)KP;

    // frame coord: xf = x' + 1 = (gx+1)*2 + 1; fold into fma constant (+3).
    // Clamp to [0, 5.99994]: equivalent to zero-pad sampling in the 7-frame
    // (edge-clamp error <= 1e-4*|v|, far below threshold). x0 in [0,5],
    // reads [0,6] -> 7-wide frame, no masks, no bounds checks.
    auto sample = [&](float Bi, float Bj, float Bl) -> float {
        float xf = fmaf(Bi, R00, fmaf(Bj, R10, fmaf(Bl, R20, 3.0f)));
        float yf = fmaf(Bi, R01, fmaf(Bj, R11, fmaf(Bl, R21, 3.0f)));
        float zf = fmaf(Bi, R02, fmaf(Bj, R12, fmaf(Bl, R22, 3.0f)));
        xf = fminf(fmaxf(xf, 0.0f), 5.99993896f);   // -> v_med3-ish, 2 ops
        yf = fminf(fmaxf(yf, 0.0f), 5.99993896f);
        zf = fminf(fmaxf(zf, 0.0f), 5.99993896f);
        const int x0 = (int)xf, y0 = (int)yf, z0 = (int)zf;  // trunc==floor (>=0)
        const float wx = __builtin_amdgcn_fractf(xf);
        const float wy = __builtin_amdgcn_fractf(yf);
        const float wz = __builtin_amdgcn_fractf(zf);
        const int ci = z0 * 49 + y0 * 7 + x0;        // in [0, 285]

        // pairs -> 4x ds_read2_b32, offsets (0,1)(7,8)(49,50)(56,57)
        const float a00 = pw[ci],      a01 = pw[ci + 1];
        const float a10 = pw[ci + 7],  a11 = pw[ci + 8];
        const float a20 = pw[ci + 49], a21 = pw[ci + 50];
        const float a30 = pw[ci + 56], a31 = pw[ci + 57];

        const float r0 = fmaf(wx, a01 - a00, a00);
        const float r1 = fmaf(wx, a11 - a10, a10);
        const float r2 = fmaf(wx, a21 - a20, a20);
        const float r3 = fmaf(wx, a31 - a30, a30);
        const float s0 = fmaf(wy, r1 - r0, r0);
        const float s1 = fmaf(wy, r3 - r2, r2);
        return fmaf(wz, s1 - s0, s0);
    };

    on[p0] = sample((float)(i0 - 2), (float)(j0 - 2), (float)(l0 - 2));
    if (p1 < KP)
        on[p1] = sample((float)(i1 - 2), (float)(j1 - 2), (float)(l1 - 2));
}

extern "C" void kernel_launch(void* const* d_in, const int* in_sizes, int n_in,
                              void* d_out, int out_size, void* d_ws, size_t ws_size,
                              hipStream_t stream) {
    const float* vol     = (const float*)d_in[0];
    const float* theta_v = (const float*)d_in[1];
    const float* theta   = (const float*)d_in[2];
    float* out           = (float*)d_out;

    const int N = in_sizes[2];          // 262144, divisible by FPB
    fastrot_kernel<<<N / FPB, FPB * 64, 0, stream>>>(vol, theta_v, theta, out);
}

// Round 5
// 79.355 us; speedup vs baseline: 1.0304x; 1.0304x over previous
//
#include <hip/hip_runtime.h>
#include <math.h>

#define KP   125        // 5*5*5 filter taps
#define VOL7 344        // 7*7*7 = 343 zero-frame volume, rounded to /4
#define FPB  8          // one wave per filter, 8 filters per 512-thread block

typedef float f32x2 __attribute__((ext_vector_type(2)));

static __device__ __forceinline__ f32x2 pkfma(f32x2 a, f32x2 b, f32x2 c) {
    return __builtin_elementwise_fma(a, b, c);
}

__global__ __launch_bounds__(FPB * 64) void fastrot_kernel(
    const float* __restrict__ vol,      // N*125
    const float* __restrict__ theta_v,  // N*3
    const float* __restrict__ theta,    // N
    float* __restrict__ out)            // N*125
{
    __shared__ __align__(16) float pad[FPB][VOL7];
    __shared__ __align__(8)  float sR[FPB][12];   // R packed {00,01,10,11,20,21,02,12,22}

    const int lane = threadIdx.x & 63;
    const int wv   = threadIdx.x >> 6;
    const long long nb = (long long)blockIdx.x * FPB;
    const long long n  = nb + wv;

    // ---- zero-fill 7^3 frame (wave-private; intra-wave ordering suffices) ----
    float4* p4 = (float4*)(&pad[wv][0]);
    const float4 z4 = make_float4(0.f, 0.f, 0.f, 0.f);
    p4[lane] = z4;
    if (lane < (VOL7 / 4 - 64)) p4[lane + 64] = z4;   // 86 float4 total

    // ---- load this filter's 125 values (coalesced, 2 loads/lane) ----
    const float* vn = vol + n * (long long)KP;
    const int p0 = lane, p1 = lane + 64;
    const float fv0 = vn[p0];
    const float fv1 = (p1 < KP) ? vn[p1] : 0.0f;

    // p -> (i,j,l), exact magic-mul for p < 128
    const int i0 = (p0 * 41) >> 10;
    const int q0 = (p0 * 205) >> 10;
    const int j0 = q0 - i0 * 5;
    const int l0 = p0 - q0 * 5;
    const int i1 = (p1 * 41) >> 10;
    const int q1 = (p1 * 205) >> 10;
    const int j1 = q1 - i1 * 5;
    const int l1 = p1 - q1 * 5;

    // ---- scatter interior into frame: idx = 49(i+1)+7(j+1)+(l+1) ----
    pad[wv][i0 * 49 + j0 * 7 + l0 + 57] = fv0;
    if (p1 < KP) pad[wv][i1 * 49 + j1 * 7 + l1 + 57] = fv1;

    // ---- wave 0 computes Rodrigues for all FPB filters (amortized) ----
    if (wv == 0 && lane < FPB) {
        const long long m = nb + lane;
        const float ax = theta_v[m * 3 + 0];
        const float ay = theta_v[m * 3 + 1];
        const float az = theta_v[m * 3 + 2];
        const float th = theta[m];
        const float d2  = ax * ax + ay * ay + az * az;
        const float inv = rsqrtf(fmaxf(d2, 1e-24f));
        const float vx = ax * inv, vy = ay * inv, vz = az * inv;
        float s, cth;
        __sincosf(th, &s, &cth);
        const float c = 1.0f - cth;
        float* R = &sR[lane][0];
        R[0] = 1.0f - c * (vy * vy + vz * vz);   // R00
        R[1] = -s * vz + c * (vx * vy);          // R01
        R[2] =  s * vz + c * (vx * vy);          // R10
        R[3] = 1.0f - c * (vx * vx + vz * vz);   // R11
        R[4] = -s * vy + c * (vx * vz);          // R20
        R[5] =  s * vx + c * (vy * vz);          // R21
        R[6] =  s * vy + c * (vx * vz);          // R02
        R[7] = -s * vx + c * (vy * vz);          // R12
        R[8] = 1.0f - c * (vx * vx + vy * vy);   // R22
    }

    __syncthreads();   // R published (fill/scatter are wave-private)

    // ---- read R: {R00,R01},{R10,R11},{R20,R21} pairs + z column ----
    const f32x2 Rp0 = *(const f32x2*)&sR[wv][0];
    const f32x2 Rp1 = *(const f32x2*)&sR[wv][2];
    const f32x2 Rp2 = *(const f32x2*)&sR[wv][4];
    const float Rz0 = sR[wv][6], Rz1 = sR[wv][7], Rz2 = sR[wv][8];

    const float* pw = &pad[wv][0];
    float* on = out + n * (long long)KP;

    // frame coord: xf = (gx+1)*2 + 1, folded const = +3. Clamp to [0, 5.99994]
    // == zero-pad sampling in the 7-frame (error <= 1e-4*|v| << threshold).
    auto sample = [&](float Bi, float Bj, float Bl) -> float {
        const f32x2 Bi2 = {Bi, Bi}, Bj2 = {Bj, Bj}, Bl2 = {Bl, Bl};
        f32x2 xy = pkfma(Bi2, Rp0, pkfma(Bj2, Rp1, pkfma(Bl2, Rp2, (f32x2){3.0f, 3.0f})));
        float zf = fmaf(Bi, Rz0, fmaf(Bj, Rz1, fmaf(Bl, Rz2, 3.0f)));
        xy = __builtin_elementwise_min(
                 __builtin_elementwise_max(xy, (f32x2){0.0f, 0.0f}),
                 (f32x2){5.99993896f, 5.99993896f});
        zf = fminf(fmaxf(zf, 0.0f), 5.99993896f);
        const int x0 = (int)xy.x, y0 = (int)xy.y, z0 = (int)zf;
        const float wx = __builtin_amdgcn_fractf(xy.x);
        const float wy = __builtin_amdgcn_fractf(xy.y);
        const float wz = __builtin_amdgcn_fractf(zf);
        const int ci = z0 * 49 + y0 * 7 + x0;        // in [0, 285]

        // z-paired loads -> ds_read2_b32 into natural VGPR pairs:
        // a0={v(ci),v(ci+49)} a1={+1,+50} a2={+7,+56} a3={+8,+57}
        const f32x2 a0 = {pw[ci],     pw[ci + 49]};
        const f32x2 a1 = {pw[ci + 1], pw[ci + 50]};
        const f32x2 a2 = {pw[ci + 7], pw[ci + 56]};
        const f32x2 a3 = {pw[ci + 8], pw[ci + 57]};

        const f32x2 wx2 = {wx, wx}, wy2 = {wy, wy};
        const f32x2 r02 = pkfma(wx2, a1 - a0, a0);   // {r0, r2} (z=0, z=1)
        const f32x2 r13 = pkfma(wx2, a3 - a2, a2);   // {r1, r3}
        const f32x2 s01 = pkfma(wy2, r13 - r02, r02);// {s0, s1}
        return fmaf(wz, s01.y - s01.x, s01.x);
    };

    on[p0] = sample((float)(i0 - 2), (float)(j0 - 2), (float)(l0 - 2));
    if (p1 < KP)
        on[p1] = sample((float)(i1 - 2), (float)(j1 - 2), (float)(l1 - 2));
}

extern "C" void kernel_launch(void* const* d_in, const int* in_sizes, int n_in,
                              void* d_out, int out_size, void* d_ws, size_t ws_size,
                              hipStream_t stream) {
    const float* vol     = (const float*)d_in[0];
    const float* theta_v = (const float*)d_in[1];
    const float* theta   = (const float*)d_in[2];
    float* out           = (float*)d_out;

    const int N = in_sizes[2];          // 262144, divisible by FPB
    fastrot_kernel<<<N / FPB, FPB * 64, 0, stream>>>(vol, theta_v, theta, out);
}

// Round 6
// 78.259 us; speedup vs baseline: 1.0448x; 1.0140x over previous
//
#include <hip/hip_runtime.h>
#include <math.h>

#define KP   125        // 5*5*5 filter taps
#define VOL7 344        // 7*7*7 = 343 zero-frame volume, rounded to /4
#define FPB  4          // one wave per filter, 4 filters per 256-thread block

// ---------- Kernel A: per-filter Rodrigues -> Rws[n*12 + 0..8] ----------
__global__ __launch_bounds__(256) void rodrigues_kernel(
    const float* __restrict__ theta_v,  // N*3
    const float* __restrict__ theta,    // N
    float* __restrict__ Rws, int N)
{
    const int n = blockIdx.x * 256 + threadIdx.x;
    if (n >= N) return;
    const float ax = theta_v[n * 3 + 0];
    const float ay = theta_v[n * 3 + 1];
    const float az = theta_v[n * 3 + 2];
    const float th = theta[n];
    const float d2  = ax * ax + ay * ay + az * az;
    const float inv = rsqrtf(fmaxf(d2, 1e-24f));
    const float vx = ax * inv, vy = ay * inv, vz = az * inv;
    float s, cth;
    __sincosf(th, &s, &cth);
    const float c = 1.0f - cth;
    float4 r0, r1, r2;
    r0.x = 1.0f - c * (vy * vy + vz * vz);   // R00
    r0.y = -s * vz + c * (vx * vy);          // R01
    r0.z =  s * vy + c * (vx * vz);          // R02
    r0.w =  s * vz + c * (vx * vy);          // R10
    r1.x = 1.0f - c * (vx * vx + vz * vz);   // R11
    r1.y = -s * vx + c * (vy * vz);          // R12
    r1.z = -s * vy + c * (vx * vz);          // R20
    r1.w =  s * vx + c * (vy * vz);          // R21
    r2.x = 1.0f - c * (vx * vx + vy * vy);   // R22
    r2.y = 0.f; r2.z = 0.f; r2.w = 0.f;
    float4* o = (float4*)(Rws + (long long)n * 12);
    o[0] = r0; o[1] = r1; o[2] = r2;
}

// ---------- Kernel B: barrier-free sample kernel (R from ws) ----------
__global__ __launch_bounds__(FPB * 64) void fastrot_kernel(
    const float* __restrict__ vol,      // N*125
    const float* __restrict__ Rws,      // N*12
    float* __restrict__ out)            // N*125
{
    __shared__ __align__(16) float pad[FPB][VOL7];

    const int lane = threadIdx.x & 63;
    // wave index is uniform; force scalarization so R/vol/out addressing is SALU
    const int wvu = __builtin_amdgcn_readfirstlane(threadIdx.x >> 6);
    const int n   = blockIdx.x * FPB + wvu;

    // ---- zero-fill 7^3 frame (wave-private; intra-wave ordering suffices) ----
    float4* p4 = (float4*)(&pad[wvu][0]);
    const float4 z4 = make_float4(0.f, 0.f, 0.f, 0.f);
    p4[lane] = z4;
    if (lane < (VOL7 / 4 - 64)) p4[lane + 64] = z4;   // 86 float4 total

    // ---- load this filter's 125 values (coalesced, 2 loads/lane) ----
    const float* vn = vol + (long long)n * KP;
    const int p0 = lane, p1 = lane + 64;
    const float fv0 = vn[p0];
    const float fv1 = (p1 < KP) ? vn[p1] : 0.0f;

    // ---- R for this wave's filter: wave-uniform scalar loads ----
    const float* Rp = Rws + (long long)n * 12;
    const float R00 = Rp[0], R01 = Rp[1], R02 = Rp[2];
    const float R10 = Rp[3], R11 = Rp[4], R12 = Rp[5];
    const float R20 = Rp[6], R21 = Rp[7], R22 = Rp[8];

    // p -> (i,j,l), exact magic-mul for p < 128
    const int i0 = (p0 * 41) >> 10;
    const int q0 = (p0 * 205) >> 10;
    const int j0 = q0 - i0 * 5;
    const int l0 = p0 - q0 * 5;
    const int i1 = (p1 * 41) >> 10;
    const int q1 = (p1 * 205) >> 10;
    const int j1 = q1 - i1 * 5;
    const int l1 = p1 - q1 * 5;

    // ---- scatter interior into frame: idx = 49(i+1)+7(j+1)+(l+1) ----
    pad[wvu][i0 * 49 + j0 * 7 + l0 + 57] = fv0;
    if (p1 < KP) pad[wvu][i1 * 49 + j1 * 7 + l1 + 57] = fv1;

    const float* pw = &pad[wvu][0];
    float* on = out + (long long)n * KP;

    // frame coord: xf = (gx+1)*2 + 1, folded const = +3. Clamp to [0, 5.99994]
    // == zero-pad sampling in the 7-frame (error <= 1e-4*|v| << threshold).
    auto sample = [&](float Bi, float Bj, float Bl) -> float {
        float xf = fmaf(Bi, R00, fmaf(Bj, R10, fmaf(Bl, R20, 3.0f)));
        float yf = fmaf(Bi, R01, fmaf(Bj, R11, fmaf(Bl, R21, 3.0f)));
        float zf = fmaf(Bi, R02, fmaf(Bj, R12, fmaf(Bl, R22, 3.0f)));
        xf = fminf(fmaxf(xf, 0.0f), 5.99993896f);
        yf = fminf(fmaxf(yf, 0.0f), 5.99993896f);
        zf = fminf(fmaxf(zf, 0.0f), 5.99993896f);
        const int x0 = (int)xf, y0 = (int)yf, z0 = (int)zf;  // trunc==floor (>=0)
        const float wx = __builtin_amdgcn_fractf(xf);
        const float wy = __builtin_amdgcn_fractf(yf);
        const float wz = __builtin_amdgcn_fractf(zf);
        const int ci = z0 * 49 + y0 * 7 + x0;        // in [0, 285]

        // pairs -> 4x ds_read2_b32, offsets (0,1)(7,8)(49,50)(56,57)
        const float a00 = pw[ci],      a01 = pw[ci + 1];
        const float a10 = pw[ci + 7],  a11 = pw[ci + 8];
        const float a20 = pw[ci + 49], a21 = pw[ci + 50];
        const float a30 = pw[ci + 56], a31 = pw[ci + 57];

        const float r0 = fmaf(wx, a01 - a00, a00);
        const float r1 = fmaf(wx, a11 - a10, a10);
        const float r2 = fmaf(wx, a21 - a20, a20);
        const float r3 = fmaf(wx, a31 - a30, a30);
        const float s0 = fmaf(wy, r1 - r0, r0);
        const float s1 = fmaf(wy, r3 - r2, r2);
        return fmaf(wz, s1 - s0, s0);
    };

    on[p0] = sample((float)(i0 - 2), (float)(j0 - 2), (float)(l0 - 2));
    if (p1 < KP)
        on[p1] = sample((float)(i1 - 2), (float)(j1 - 2), (float)(l1 - 2));
}

// ---------- Fallback: single kernel, wave0-amortized R, one barrier ----------
__global__ __launch_bounds__(512) void fastrot_fb_kernel(
    const float* __restrict__ vol,
    const float* __restrict__ theta_v,
    const float* __restrict__ theta,
    float* __restrict__ out)
{
    __shared__ __align__(16) float pad[8][VOL7];
    __shared__ float sR[8][12];

    const int lane = threadIdx.x & 63;
    const int wv   = threadIdx.x >> 6;
    const long long nb = (long long)blockIdx.x * 8;
    const long long n  = nb + wv;

    float4* p4 = (float4*)(&pad[wv][0]);
    const float4 z4 = make_float4(0.f, 0.f, 0.f, 0.f);
    p4[lane] = z4;
    if (lane < (VOL7 / 4 - 64)) p4[lane + 64] = z4;

    const float* vn = vol + n * (long long)KP;
    const int p0 = lane, p1 = lane + 64;
    const float fv0 = vn[p0];
    const float fv1 = (p1 < KP) ? vn[p1] : 0.0f;

    const int i0 = (p0 * 41) >> 10;
    const int q0 = (p0 * 205) >> 10;
    const int j0 = q0 - i0 * 5;
    const int l0 = p0 - q0 * 5;
    const int i1 = (p1 * 41) >> 10;
    const int q1 = (p1 * 205) >> 10;
    const int j1 = q1 - i1 * 5;
    const int l1 = p1 - q1 * 5;

    pad[wv][i0 * 49 + j0 * 7 + l0 + 57] = fv0;
    if (p1 < KP) pad[wv][i1 * 49 + j1 * 7 + l1 + 57] = fv1;

    if (wv == 0 && lane < 8) {
        const long long m = nb + lane;
        const float ax = theta_v[m * 3 + 0];
        const float ay = theta_v[m * 3 + 1];
        const float az = theta_v[m * 3 + 2];
        const float th = theta[m];
        const float d2  = ax * ax + ay * ay + az * az;
        const float inv = rsqrtf(fmaxf(d2, 1e-24f));
        const float vx = ax * inv, vy = ay * inv, vz = az * inv;
        float s, cth;
        __sincosf(th, &s, &cth);
        const float c = 1.0f - cth;
        float* R = &sR[lane][0];
        R[0] = 1.0f - c * (vy * vy + vz * vz);
        R[1] = -s * vz + c * (vx * vy);
        R[2] =  s * vy + c * (vx * vz);
        R[3] =  s * vz + c * (vx * vy);
        R[4] = 1.0f - c * (vx * vx + vz * vz);
        R[5] = -s * vx + c * (vy * vz);
        R[6] = -s * vy + c * (vx * vz);
        R[7] =  s * vx + c * (vy * vz);
        R[8] = 1.0f - c * (vx * vx + vy * vy);
    }

    __syncthreads();

    const float R00 = sR[wv][0], R01 = sR[wv][1], R02 = sR[wv][2];
    const float R10 = sR[wv][3], R11 = sR[wv][4], R12 = sR[wv][5];
    const float R20 = sR[wv][6], R21 = sR[wv][7], R22 = sR[wv][8];

    const float* pw = &pad[wv][0];
    float* on = out + n * (long long)KP;

    auto sample = [&](float Bi, float Bj, float Bl) -> float {
        float xf = fmaf(Bi, R00, fmaf(Bj, R10, fmaf(Bl, R20, 3.0f)));
        float yf = fmaf(Bi, R01, fmaf(Bj, R11, fmaf(Bl, R21, 3.0f)));
        float zf = fmaf(Bi, R02, fmaf(Bj, R12, fmaf(Bl, R22, 3.0f)));
        xf = fminf(fmaxf(xf, 0.0f), 5.99993896f);
        yf = fminf(fmaxf(yf, 0.0f), 5.99993896f);
        zf = fminf(fmaxf(zf, 0.0f), 5.99993896f);
        const int x0 = (int)xf, y0 = (int)yf, z0 = (int)zf;
        const float wx = __builtin_amdgcn_fractf(xf);
        const float wy = __builtin_amdgcn_fractf(yf);
        const float wz = __builtin_amdgcn_fractf(zf);
        const int ci = z0 * 49 + y0 * 7 + x0;
        const float a00 = pw[ci],      a01 = pw[ci + 1];
        const float a10 = pw[ci + 7],  a11 = pw[ci + 8];
        const float a20 = pw[ci + 49], a21 = pw[ci + 50];
        const float a30 = pw[ci + 56], a31 = pw[ci + 57];
        const float r0 = fmaf(wx, a01 - a00, a00);
        const float r1 = fmaf(wx, a11 - a10, a10);
        const float r2 = fmaf(wx, a21 - a20, a20);
        const float r3 = fmaf(wx, a31 - a30, a30);
        const float s0 = fmaf(wy, r1 - r0, r0);
        const float s1 = fmaf(wy, r3 - r2, r2);
        return fmaf(wz, s1 - s0, s0);
    };

    on[p0] = sample((float)(i0 - 2), (float)(j0 - 2), (float)(l0 - 2));
    if (p1 < KP)
        on[p1] = sample((float)(i1 - 2), (float)(j1 - 2), (float)(l1 - 2));
}

extern "C" void kernel_launch(void* const* d_in, const int* in_sizes, int n_in,
                              void* d_out, int out_size, void* d_ws, size_t ws_size,
                              hipStream_t stream) {
    const float* vol     = (const float*)d_in[0];
    const float* theta_v = (const float*)d_in[1];
    const float* theta   = (const float*)d_in[2];
    float* out           = (float*)d_out;

    const int N = in_sizes[2];          // 262144

    const size_t need = (size_t)N * 12 * sizeof(float);   // 12.6 MB
    if (ws_size >= need) {
        float* Rws = (float*)d_ws;
        rodrigues_kernel<<<(N + 255) / 256, 256, 0, stream>>>(theta_v, theta, Rws, N);
        fastrot_kernel<<<N / FPB, FPB * 64, 0, stream>>>(vol, Rws, out);
    } else {
        fastrot_fb_kernel<<<N / 8, 512, 0, stream>>>(vol, theta_v, theta, out);
    }
}